// Round 4
// baseline (861.017 us; speedup 1.0000x reference)
//
#include <hip/hip_runtime.h>
#include <hip/hip_cooperative_groups.h>

namespace cg = cooperative_groups;

// out[N,32] = segment_sum(edge_val[e] * weight[edge_col[e], :], edge_row[e]) + bias
// R4: ONE cooperative kernel (launch overhead ~30us/kernel observed): zero ->
// LDS-staged bucket hist -> scan -> reserve+scatter (agent-scope atomic stores:
// coherent + no dirty-line write amp) -> per-bucket LDS fp32 accumulate with
// 8-wide batched loads for memory-level parallelism. Fallback: R1 atomic scatter.

#define FEAT 32
#define RB 128          // rows per bucket
#define RB_BITS 7
#define MAXB 1024       // max buckets: grid = B blocks, 4 blocks/CU co-resident cap

#define ALD(p)    __hip_atomic_load((p),  __ATOMIC_RELAXED, __HIP_MEMORY_SCOPE_AGENT)
#define AST(p, v) __hip_atomic_store((p), (v), __ATOMIC_RELAXED, __HIP_MEMORY_SCOPE_AGENT)

// ---------------- fallback (R1 baseline, known-good) ----------------
__global__ __launch_bounds__(256) void gnn_init_out(
    const float* __restrict__ bias, float* __restrict__ out, int total) {
    int i = blockIdx.x * blockDim.x + threadIdx.x;
    if (i < total) out[i] = bias[i & (FEAT - 1)];
}

__global__ __launch_bounds__(256) void gnn_scatter(
    const int* __restrict__ edge_row, const int* __restrict__ edge_col,
    const float* __restrict__ edge_val, const float* __restrict__ weight,
    float* __restrict__ out, int num_edges) {
    long long t = (long long)blockIdx.x * blockDim.x + threadIdx.x;
    int e = (int)(t >> 5);
    int f = (int)(t & (FEAT - 1));
    if (e < num_edges) {
        atomicAdd(out + edge_row[e] * FEAT + f,
                  edge_val[e] * weight[edge_col[e] * FEAT + f]);
    }
}

// ---------------- R4 fused cooperative kernel ----------------
__global__ __launch_bounds__(256, 4) void k_fused(
    const int* __restrict__ edge_row, const int* __restrict__ edge_col,
    const float* __restrict__ edge_val, const float* __restrict__ weight,
    const float* __restrict__ bias, float* __restrict__ out,
    int* counts, int* start, int* cursor, unsigned long long* buf,
    int E, int N, int B, int chunk) {
    __shared__ int lc[MAXB];
    __shared__ int lbase[MAXB];
    __shared__ float accs[RB * FEAT];  // 16 KB
    __shared__ int tsum[256];
    cg::grid_group grid = cg::this_grid();
    const int tid = threadIdx.x;
    const int g = blockIdx.x;

    // ---- phase 0: zero global counters (agent atomics: coherent) + local hist
    for (int i = g * 256 + tid; i < B; i += gridDim.x * 256) AST(&counts[i], 0);
    for (int i = tid; i < B; i += 256) lc[i] = 0;
    __syncthreads();
    grid.sync();

    // ---- phase 1: per-block LDS histogram of own edge chunk, merge to global
    const int base = g * chunk;
    const int end = min(base + chunk, E);
    for (int i = base + tid; i < end; i += 256)
        atomicAdd(&lc[edge_row[i] >> RB_BITS], 1);
    __syncthreads();
    for (int b = tid; b < B; b += 256) {
        int c = lc[b];
        if (c) atomicAdd(&counts[b], c);  // device-scope, coherent
    }
    grid.sync();

    // ---- phase 2: exclusive scan of counts -> start, cursor (block 0 only)
    if (g == 0) {
        int b0 = tid * 4;
        int v0 = (b0 + 0 < B) ? ALD(&counts[b0 + 0]) : 0;
        int v1 = (b0 + 1 < B) ? ALD(&counts[b0 + 1]) : 0;
        int v2 = (b0 + 2 < B) ? ALD(&counts[b0 + 2]) : 0;
        int v3 = (b0 + 3 < B) ? ALD(&counts[b0 + 3]) : 0;
        int ssum = v0 + v1 + v2 + v3;
        tsum[tid] = ssum;
        __syncthreads();
        #pragma unroll
        for (int off = 1; off < 256; off <<= 1) {
            int t = (tid >= off) ? tsum[tid - off] : 0;
            __syncthreads();
            tsum[tid] += t;
            __syncthreads();
        }
        int ex = tsum[tid] - ssum;
        if (b0 + 0 < B) { AST(&start[b0 + 0], ex); AST(&cursor[b0 + 0], ex); } ex += v0;
        if (b0 + 1 < B) { AST(&start[b0 + 1], ex); AST(&cursor[b0 + 1], ex); } ex += v1;
        if (b0 + 2 < B) { AST(&start[b0 + 2], ex); AST(&cursor[b0 + 2], ex); } ex += v2;
        if (b0 + 3 < B) { AST(&start[b0 + 3], ex); AST(&cursor[b0 + 3], ex); }
    }
    grid.sync();

    // ---- phase 3: reserve contiguous run per (block,bucket), scatter records
    for (int b = tid; b < B; b += 256) {
        int c = lc[b];
        lbase[b] = c ? atomicAdd(&cursor[b], c) : 0;
        lc[b] = 0;  // becomes local cursor
    }
    __syncthreads();
    for (int i = base + tid; i < end; i += 256) {
        int r = edge_row[i];
        int b = r >> RB_BITS;
        int off = atomicAdd(&lc[b], 1);
        unsigned long long rec =
            ((unsigned long long)__float_as_uint(edge_val[i]) << 32) |
            (unsigned int)(edge_col[i] | ((r & (RB - 1)) << 17));
        AST(&buf[lbase[b] + off], rec);  // write-through: no dirty-line amp
    }
    grid.sync();

    // ---- phase 4: accumulate bucket g in LDS, one coalesced store per row
    {
        const int b = g;  // grid == #buckets: exactly one bucket per block
        const int s = ALD(&start[b]);
        const int c = ALD(&counts[b]);
        for (int i = tid; i < RB * FEAT; i += 256) accs[i] = 0.f;
        __syncthreads();
        const int gid = tid >> 5;
        const int f = tid & 31;
        const int gs = s + (int)(((long long)c * gid) >> 3);
        const int ge = s + (int)(((long long)c * (gid + 1)) >> 3);
        int i = gs;
        for (; i + 8 <= ge; i += 8) {  // 8 independent chains -> MLP
            unsigned long long rr[8];
            #pragma unroll
            for (int k = 0; k < 8; ++k) rr[k] = ALD(&buf[i + k]);
            float vv[8], wv[8];
            int rl[8];
            #pragma unroll
            for (int k = 0; k < 8; ++k) {
                unsigned int lo = (unsigned int)rr[k];
                int cc = lo & 0x1FFFF;
                rl[k] = (lo >> 17) & (RB - 1);
                vv[k] = __uint_as_float((unsigned int)(rr[k] >> 32));
                wv[k] = weight[cc * FEAT + f];
            }
            #pragma unroll
            for (int k = 0; k < 8; ++k)
                atomicAdd(&accs[rl[k] * FEAT + f], vv[k] * wv[k]);
        }
        for (; i < ge; ++i) {
            unsigned long long p = ALD(&buf[i]);
            unsigned int lo = (unsigned int)p;
            int cc = lo & 0x1FFFF;
            int rl = (lo >> 17) & (RB - 1);
            float v = __uint_as_float((unsigned int)(p >> 32));
            atomicAdd(&accs[rl * FEAT + f], v * weight[cc * FEAT + f]);
        }
        __syncthreads();
        const float bf = bias[f];
        const int rbase = b * RB;
        for (int r = gid; r < RB; r += 8) {
            int row = rbase + r;
            if (row < N) out[row * FEAT + f] = accs[r * FEAT + f] + bf;
        }
    }
}

extern "C" void kernel_launch(void* const* d_in, const int* in_sizes, int n_in,
                              void* d_out, int out_size, void* d_ws, size_t ws_size,
                              hipStream_t stream) {
    const int*   edge_row = (const int*)d_in[0];
    const int*   edge_col = (const int*)d_in[1];
    const float* edge_val = (const float*)d_in[2];
    const float* weight   = (const float*)d_in[3];
    const float* bias     = (const float*)d_in[4];
    float* out = (float*)d_out;

    const int E = in_sizes[0];
    const int N = out_size / FEAT;
    const int B = (N + RB - 1) / RB;

    // ws layout: counts[B] | start[B] | cursor[B] | pad | buf[E] u64
    size_t buf_off = (((size_t)3 * B) * 4 + 15) & ~(size_t)15;
    size_t need = buf_off + (size_t)E * 8;

    bool ok = (ws_size >= need) && (B <= MAXB) && (N <= (1 << 17)) && (E > 0);
    if (ok) {
        int* counts = (int*)d_ws;
        int* startp = counts + B;
        int* cursor = startp + B;
        unsigned long long* buf = (unsigned long long*)((char*)d_ws + buf_off);
        int chunk = (E + B - 1) / B;

        const int* a0 = edge_row; const int* a1 = edge_col;
        const float* a2 = edge_val; const float* a3 = weight; const float* a4 = bias;
        float* a5 = out;
        int e_ = E, n_ = N, b_ = B, ch_ = chunk;
        void* args[] = {(void*)&a0, (void*)&a1, (void*)&a2, (void*)&a3, (void*)&a4,
                        (void*)&a5, (void*)&counts, (void*)&startp, (void*)&cursor,
                        (void*)&buf, (void*)&e_, (void*)&n_, (void*)&b_, (void*)&ch_};
        hipError_t err = hipLaunchCooperativeKernel((const void*)k_fused, dim3(B),
                                                    dim3(256), args, 0, stream);
        if (err == hipSuccess) return;
    }
    // fallback: R1 atomic scatter
    gnn_init_out<<<(out_size + 255) / 256, 256, 0, stream>>>(bias, out, out_size);
    long long threads = (long long)E * FEAT;
    gnn_scatter<<<(int)((threads + 255) / 256), 256, 0, stream>>>(
        edge_row, edge_col, edge_val, weight, out, E);
}

// Round 5
// 261.797 us; speedup vs baseline: 3.2889x; 3.2889x over previous
//
#include <hip/hip_runtime.h>

// out[N,32] = segment_sum(edge_val[e] * weight[edge_col[e], :], edge_row[e]) + bias
// R5: XCD-sliced atomic scatter. Rows split into 8 slices (1.6MB each -> resident
// in one XCD's 4MB L2). Block g = (slice g&7, edge-chunk g>>3); consecutive blocks
// round-robin across XCDs on MI355X, so all blocks of a slice share one XCD and
// their atomics RMW L2-resident lines instead of thrashing to HBM (R1 showed
// WRITE_SIZE == E*128B: one line-writeback per edge). Edge arrays read with
// nontemporal loads to avoid evicting the out slice. Same atomic count as R1;
// the delta isolates the locality effect.

#define FEAT 32
#define NSLICE 8

__global__ __launch_bounds__(256) void gnn_init_out(
    const float* __restrict__ bias, float* __restrict__ out, int total) {
    int i = blockIdx.x * blockDim.x + threadIdx.x;
    if (i < total) out[i] = bias[i & (FEAT - 1)];
}

__global__ __launch_bounds__(256) void k_slice_scatter(
    const int* __restrict__ edge_row, const int* __restrict__ edge_col,
    const float* __restrict__ edge_val, const float* __restrict__ weight,
    float* __restrict__ out, int E, int rows_per_slice, int chunk) {
    const int g = blockIdx.x;
    const int s = g & (NSLICE - 1);   // slice id == XCD id (round-robin heuristic)
    const int q = g >> 3;             // edge chunk id
    const int lo = s * rows_per_slice;
    const int hi = lo + rows_per_slice;
    const int base = q * chunk;
    const int end = min(base + chunk, E);
    const int wave = threadIdx.x >> 6;  // 4 waves per block
    const int lane = threadIdx.x & 63;
    const int f = lane & 31;

    for (int w = base + wave * 64; w < end; w += 4 * 64) {
        int idx = w + lane;
        int r = -1;
        if (idx < end) r = __builtin_nontemporal_load(&edge_row[idx]);
        bool m = (r >= lo) && (r < hi);
        unsigned long long mask = __ballot(m);
        // consume matches two edges per iteration (lanes 0-31 -> j0, 32-63 -> j1)
        while (mask) {
            int j0 = __ffsll((long long)mask) - 1;
            mask &= mask - 1;
            int j1 = -1;
            if (mask) { j1 = __ffsll((long long)mask) - 1; mask &= mask - 1; }
            int j = (lane < 32) ? j0 : j1;
            int jj = (j >= 0) ? j : 0;
            int rr = __shfl(r, jj);           // row broadcast from matching lane
            if (j >= 0) {
                int e = w + j;
                int c = __builtin_nontemporal_load(&edge_col[e]);   // broadcast
                float v = __builtin_nontemporal_load(&edge_val[e]); // broadcast
                float wgt = weight[(size_t)c * FEAT + f];           // 128B row gather
                atomicAdd(out + (size_t)rr * FEAT + f, v * wgt);    // L2-resident line
            }
        }
    }
}

// known-good fallback (R1) in case grid math ever degenerates
__global__ __launch_bounds__(256) void gnn_scatter(
    const int* __restrict__ edge_row, const int* __restrict__ edge_col,
    const float* __restrict__ edge_val, const float* __restrict__ weight,
    float* __restrict__ out, int num_edges) {
    long long t = (long long)blockIdx.x * blockDim.x + threadIdx.x;
    int e = (int)(t >> 5);
    int f = (int)(t & (FEAT - 1));
    if (e < num_edges) {
        atomicAdd(out + edge_row[e] * FEAT + f,
                  edge_val[e] * weight[edge_col[e] * FEAT + f]);
    }
}

extern "C" void kernel_launch(void* const* d_in, const int* in_sizes, int n_in,
                              void* d_out, int out_size, void* d_ws, size_t ws_size,
                              hipStream_t stream) {
    const int*   edge_row = (const int*)d_in[0];
    const int*   edge_col = (const int*)d_in[1];
    const float* edge_val = (const float*)d_in[2];
    const float* weight   = (const float*)d_in[3];
    const float* bias     = (const float*)d_in[4];
    float* out = (float*)d_out;

    const int E = in_sizes[0];
    const int N = out_size / FEAT;

    gnn_init_out<<<(out_size + 255) / 256, 256, 0, stream>>>(bias, out, out_size);

    const int rows_per_slice = (N + NSLICE - 1) / NSLICE;  // 12500 @ N=100k
    const int nchunks = 256;                                // grid = 8 * 256 = 2048
    const int chunk = (E + nchunks - 1) / nchunks;          // 6250 @ E=1.6M
    if (rows_per_slice > 0 && chunk > 0) {
        k_slice_scatter<<<NSLICE * nchunks, 256, 0, stream>>>(
            edge_row, edge_col, edge_val, weight, out, E, rows_per_slice, chunk);
    } else {
        long long threads = (long long)E * FEAT;
        gnn_scatter<<<(int)((threads + 255) / 256), 256, 0, stream>>>(
            edge_row, edge_col, edge_val, weight, out, E);
    }
}